// Round 5
// baseline (240.783 us; speedup 1.0000x reference)
//
#include <hip/hip_runtime.h>
#include <hip/hip_cooperative_groups.h>
#include <math.h>

namespace cg = cooperative_groups;

// ---------------------------------------------------------------------------
// FocalLoss: geodetic->ECEF->ENU error -> distance -> focal-weighted RMS.
//
// R5: single cooperative kernel. Inputs read once (96 MB); per-block dist
// kept in LDS (<=32KB); grid.sync() -> every block folds the 512-entry
// blockmax array itself (no atomics, no extra kernel); focal phase from LDS;
// grid.sync(); block 0 folds partials. HBM floor ~96MB/6.3TBps ~= 15us.
// Fallback: R4 4-kernel path if B exceeds coop capacity (512*2048*4).
// ---------------------------------------------------------------------------

#define THREADS 256
#define GRID 512
#define GPB_MAX 2048          // groups (of 4 elems) per block, LDS = 32 KB
#define PART_OFF 64
#define PART2_OFF (64 + GRID * 4)        // doubles, 8-aligned (64+2048)
#define PART_CAP 8192
#define DIST_OFF (65600)      // fallback path scratch

// Branchless double sincos for |x| <= ~3.15 (no Payne-Hanek).
__device__ __forceinline__ void sincos_small(double x, double& s_out, double& c_out) {
    const double TWO_OVER_PI = 0.636619772367581343076;
    const double PIO2_HI = 1.57079632679489655800e+00;
    const double PIO2_LO = 6.12323399573676603587e-17;
    double kd = rint(x * TWO_OVER_PI);          // k in {-2..2}
    int q = ((int)kd) & 3;
    double r = fma(-kd, PIO2_HI, x);
    r = fma(-kd, PIO2_LO, r);
    double r2 = r * r;

    double ps = 1.58969099521155010221e-10;
    ps = fma(ps, r2, -2.50507602534068634195e-08);
    ps = fma(ps, r2, 2.75573137070700676789e-06);
    ps = fma(ps, r2, -1.98412698298579493134e-04);
    ps = fma(ps, r2, 8.33333333332248946124e-03);
    ps = fma(ps, r2, -1.66666666666666324348e-01);
    double s = fma(r2 * r, ps, r);

    double pc = -1.13596475577881948265e-11;
    pc = fma(pc, r2, 2.08757232129817482790e-09);
    pc = fma(pc, r2, -2.75573143513906633035e-07);
    pc = fma(pc, r2, 2.48015872894767294178e-05);
    pc = fma(pc, r2, -1.38888888888741095749e-03);
    pc = fma(pc, r2, 4.16666666666666019037e-02);
    double c = fma(r2 * r2, pc, fma(-0.5, r2, 1.0));

    double sr = (q & 1) ? c : s;
    double cr = (q & 1) ? s : c;
    sr = (q & 2) ? -sr : sr;
    cr = ((q + 1) & 2) ? -cr : cr;
    s_out = sr;
    c_out = cr;
}

__device__ __forceinline__ float dist_one(float latd, float lond, float hf,
                                          float px, float py, float pz) {
    const float D2R = (float)0.017453292519943295;  // fp32 deg2rad, matches numpy
    float latr = latd * D2R;
    float lonr = lond * D2R;

    double sl, cl, so, co;
    sincos_small((double)latr, sl, cl);
    sincos_small((double)lonr, so, co);
    double h = (double)hf;

    const double A  = 6378137.0;
    const double E2 = 0.00669437999014;
    double w = fma(-E2 * sl, sl, 1.0);          // in [0.9933, 1]
    double y = fma(-0.5, w, 1.5);               // linear rsqrt seed
    y = y * fma(-0.5 * w, y * y, 1.5);          // 2 Newton steps -> ~1e-19
    y = y * fma(-0.5 * w, y * y, 1.5);
    double N  = A * y;
    double Nh = N + h;
    double x  = Nh * cl * co;
    double yy = Nh * cl * so;
    double z  = fma(N, -E2, N + h) * sl;        // (N*(1-E2)+h)*sl

    double dx = (double)px - x;
    double dy = (double)py - yy;
    double dz = (double)pz - z;

    double e = -so * dx + co * dy;
    double n = -sl * co * dx - sl * so * dy + cl * dz;
    double u =  cl * co * dx + cl * so * dy + sl * dz;

    return sqrtf((float)(e * e + n * n + u * u));
}

__device__ __forceinline__ double focal2(float d, float denom) {
    float g = 2.0f * __expf(-d);                  // dynamic gamma (SCALE=1, GAMMA=2)
    float b = 1.0f - sqrtf(d / denom);            // true div: max elem ratio <= 1
    b = fmaxf(b, 0.0f);
    float wgt = __builtin_amdgcn_exp2f(g * __log2f(b));  // b^g; log2(0)->-inf->0 ok
    float fl = wgt * d;                           // ALPHA = 1
    return (double)fl * (double)fl;
}

// ---------------------------------------------------------------------------
// Fused cooperative kernel
// ---------------------------------------------------------------------------
__global__ __launch_bounds__(THREADS, 2)
void k_fused(const float* __restrict__ inp,
             const float* __restrict__ tgt,
             float* __restrict__ blockmax,
             double* __restrict__ partials,
             float* __restrict__ out,
             long B) {
    cg::grid_group grid = cg::this_grid();
    __shared__ float dist_lds[GPB_MAX * 4];      // 32 KB
    __shared__ float smax[THREADS / 64];
    __shared__ double sacc[THREADS / 64];
    __shared__ float sbcast;

    long ngroups = (B + 3) >> 2;
    long gpb = (ngroups + gridDim.x - 1) / gridDim.x;
    long g0 = (long)blockIdx.x * gpb;
    long g1 = g0 + gpb; if (g1 > ngroups) g1 = ngroups;
    int tid = threadIdx.x;

    // ---- phase 1: distances -> LDS, local max ----
    float lmax = 0.0f;
    for (long g = g0 + tid; g < g1; g += THREADS) {
        long base = g << 2;
        int li = (int)(g - g0) << 2;
        if (base + 3 < B) {
            const float4* t4 = (const float4*)(tgt + 3 * base);   // 48B, 16B-aligned
            float4 ta = t4[0], tb = t4[1], tc = t4[2];
            const float4* p4 = (const float4*)(inp + 3 * base);
            float4 pa = p4[0], pb = p4[1], pc = p4[2];
            float d0 = dist_one(ta.x, ta.y, ta.z, pa.x, pa.y, pa.z);
            float d1 = dist_one(ta.w, tb.x, tb.y, pa.w, pb.x, pb.y);
            float d2 = dist_one(tb.z, tb.w, tc.x, pb.z, pb.w, pc.x);
            float d3 = dist_one(tc.y, tc.z, tc.w, pc.y, pc.z, pc.w);
            *(float4*)(dist_lds + li) = make_float4(d0, d1, d2, d3);
            lmax = fmaxf(lmax, fmaxf(fmaxf(d0, d1), fmaxf(d2, d3)));
        } else {
            for (long i = base; i < B; ++i) {
                float d = dist_one(tgt[3*i], tgt[3*i+1], tgt[3*i+2],
                                   inp[3*i], inp[3*i+1], inp[3*i+2]);
                dist_lds[li + (int)(i - base)] = d;
                lmax = fmaxf(lmax, d);
            }
        }
    }
    for (int off = 32; off > 0; off >>= 1)
        lmax = fmaxf(lmax, __shfl_down(lmax, off, 64));
    if ((tid & 63) == 0) smax[tid >> 6] = lmax;
    __syncthreads();
    if (tid == 0) {
        float m = smax[0];
        for (int w = 1; w < THREADS / 64; ++w) m = fmaxf(m, smax[w]);
        blockmax[blockIdx.x] = m;
    }

    grid.sync();

    // ---- phase 2: every block folds global max itself (512 floats, L2-hot) ----
    float m = 0.0f;
    for (int i = tid; i < (int)gridDim.x; i += THREADS) m = fmaxf(m, blockmax[i]);
    for (int off = 32; off > 0; off >>= 1)
        m = fmaxf(m, __shfl_down(m, off, 64));
    if ((tid & 63) == 0) smax[tid >> 6] = m;
    __syncthreads();
    if (tid == 0) {
        float mm = smax[0];
        for (int w = 1; w < THREADS / 64; ++w) mm = fmaxf(mm, smax[w]);
        sbcast = mm;
    }
    __syncthreads();
    float denom = sbcast + 1e-8f;

    // ---- phase 3: focal from LDS, block partial ----
    double acc = 0.0;
    for (long g = g0 + tid; g < g1; g += THREADS) {
        long base = g << 2;
        int li = (int)(g - g0) << 2;
        if (base + 3 < B) {
            float4 d4 = *(const float4*)(dist_lds + li);
            acc += focal2(d4.x, denom) + focal2(d4.y, denom)
                 + focal2(d4.z, denom) + focal2(d4.w, denom);
        } else {
            for (long i = base; i < B; ++i)
                acc += focal2(dist_lds[li + (int)(i - base)], denom);
        }
    }
    for (int off = 32; off > 0; off >>= 1)
        acc += __shfl_down(acc, off, 64);
    if ((tid & 63) == 0) sacc[tid >> 6] = acc;
    __syncthreads();
    if (tid == 0) {
        double s = sacc[0];
        for (int w = 1; w < THREADS / 64; ++w) s += sacc[w];
        partials[blockIdx.x] = s;
    }

    grid.sync();

    // ---- phase 4: block 0 folds partials -> scalar ----
    if (blockIdx.x == 0) {
        double a = 0.0;
        for (int i = tid; i < (int)gridDim.x; i += THREADS) a += partials[i];
        for (int off = 32; off > 0; off >>= 1)
            a += __shfl_down(a, off, 64);
        if ((tid & 63) == 0) sacc[tid >> 6] = a;
        __syncthreads();
        if (tid == 0) {
            double s = sacc[0];
            for (int w = 1; w < THREADS / 64; ++w) s += sacc[w];
            out[0] = (float)sqrt(s / (double)B);
        }
    }
}

// ---------------------------------------------------------------------------
// Fallback path (proven R4 pipeline) for B beyond coop capacity
// ---------------------------------------------------------------------------
__global__ void k_pass1(const float* __restrict__ inp, const float* __restrict__ tgt,
                        float* __restrict__ dist_arr, float* __restrict__ blockmax, long B) {
    long ngroups = (B + 3) >> 2;
    long gstride = (long)gridDim.x * blockDim.x;
    float lmax = 0.0f;
    for (long g = (long)blockIdx.x * blockDim.x + threadIdx.x; g < ngroups; g += gstride) {
        long base = g << 2;
        if (base + 3 < B) {
            const float4* t4 = (const float4*)(tgt + 3 * base);
            float4 ta = t4[0], tb = t4[1], tc = t4[2];
            const float4* p4 = (const float4*)(inp + 3 * base);
            float4 pa = p4[0], pb = p4[1], pc = p4[2];
            float d0 = dist_one(ta.x, ta.y, ta.z, pa.x, pa.y, pa.z);
            float d1 = dist_one(ta.w, tb.x, tb.y, pa.w, pb.x, pb.y);
            float d2 = dist_one(tb.z, tb.w, tc.x, pb.z, pb.w, pc.x);
            float d3 = dist_one(tc.y, tc.z, tc.w, pc.y, pc.z, pc.w);
            if (dist_arr) *(float4*)(dist_arr + base) = make_float4(d0, d1, d2, d3);
            lmax = fmaxf(lmax, fmaxf(fmaxf(d0, d1), fmaxf(d2, d3)));
        } else {
            for (long i = base; i < B; ++i) {
                float d = dist_one(tgt[3*i], tgt[3*i+1], tgt[3*i+2],
                                   inp[3*i], inp[3*i+1], inp[3*i+2]);
                if (dist_arr) dist_arr[i] = d;
                lmax = fmaxf(lmax, d);
            }
        }
    }
    for (int off = 32; off > 0; off >>= 1)
        lmax = fmaxf(lmax, __shfl_down(lmax, off, 64));
    __shared__ float smax[THREADS / 64];
    if ((threadIdx.x & 63) == 0) smax[threadIdx.x >> 6] = lmax;
    __syncthreads();
    if (threadIdx.x == 0) {
        float m = smax[0];
        for (int w = 1; w < THREADS / 64; ++w) m = fmaxf(m, smax[w]);
        blockmax[blockIdx.x] = m;
    }
}

__global__ void k_max(const float* __restrict__ blockmax, int n, float* __restrict__ maxslot) {
    float m = 0.0f;
    for (int i = threadIdx.x; i < n; i += blockDim.x) m = fmaxf(m, blockmax[i]);
    for (int off = 32; off > 0; off >>= 1)
        m = fmaxf(m, __shfl_down(m, off, 64));
    __shared__ float smax[THREADS / 64];
    if ((threadIdx.x & 63) == 0) smax[threadIdx.x >> 6] = m;
    __syncthreads();
    if (threadIdx.x == 0) {
        float mm = smax[0];
        for (int w = 1; w < THREADS / 64; ++w) mm = fmaxf(mm, smax[w]);
        *maxslot = mm;
    }
}

__global__ void k_pass2(const float* __restrict__ dist_arr, const float* __restrict__ inp,
                        const float* __restrict__ tgt, const float* __restrict__ maxslot,
                        double* __restrict__ partials, long B) {
    float denom = *maxslot + 1e-8f;
    long ngroups = (B + 3) >> 2;
    long gstride = (long)gridDim.x * blockDim.x;
    double acc = 0.0;
    for (long g = (long)blockIdx.x * blockDim.x + threadIdx.x; g < ngroups; g += gstride) {
        long base = g << 2;
        if (base + 3 < B) {
            float d0, d1, d2, d3;
            if (dist_arr) {
                float4 d4 = *(const float4*)(dist_arr + base);
                d0 = d4.x; d1 = d4.y; d2 = d4.z; d3 = d4.w;
            } else {
                const float4* t4 = (const float4*)(tgt + 3 * base);
                float4 ta = t4[0], tb = t4[1], tc = t4[2];
                const float4* p4 = (const float4*)(inp + 3 * base);
                float4 pa = p4[0], pb = p4[1], pc = p4[2];
                d0 = dist_one(ta.x, ta.y, ta.z, pa.x, pa.y, pa.z);
                d1 = dist_one(ta.w, tb.x, tb.y, pa.w, pb.x, pb.y);
                d2 = dist_one(tb.z, tb.w, tc.x, pb.z, pb.w, pc.x);
                d3 = dist_one(tc.y, tc.z, tc.w, pc.y, pc.z, pc.w);
            }
            acc += focal2(d0, denom) + focal2(d1, denom)
                 + focal2(d2, denom) + focal2(d3, denom);
        } else {
            for (long i = base; i < B; ++i) {
                float d = dist_arr ? dist_arr[i]
                                   : dist_one(tgt[3*i], tgt[3*i+1], tgt[3*i+2],
                                              inp[3*i], inp[3*i+1], inp[3*i+2]);
                acc += focal2(d, denom);
            }
        }
    }
    for (int off = 32; off > 0; off >>= 1)
        acc += __shfl_down(acc, off, 64);
    __shared__ double lds[THREADS / 64];
    if ((threadIdx.x & 63) == 0) lds[threadIdx.x >> 6] = acc;
    __syncthreads();
    if (threadIdx.x == 0) {
        double s = lds[0];
        for (int w = 1; w < THREADS / 64; ++w) s += lds[w];
        partials[blockIdx.x] = s;
    }
}

__global__ void k_final(const double* __restrict__ partials, int nparts,
                        float* __restrict__ out, long B) {
    double acc = 0.0;
    for (int i = threadIdx.x; i < nparts; i += blockDim.x) acc += partials[i];
    for (int off = 32; off > 0; off >>= 1)
        acc += __shfl_down(acc, off, 64);
    __shared__ double lds[THREADS / 64];
    if ((threadIdx.x & 63) == 0) lds[threadIdx.x >> 6] = acc;
    __syncthreads();
    if (threadIdx.x == 0) {
        double s = lds[0];
        for (int w = 1; w < THREADS / 64; ++w) s += lds[w];
        out[0] = (float)sqrt(s / (double)B);
    }
}

extern "C" void kernel_launch(void* const* d_in, const int* in_sizes, int n_in,
                              void* d_out, int out_size, void* d_ws, size_t ws_size,
                              hipStream_t stream) {
    const float* inp = (const float*)d_in[0];   // (B,3) predicted ECEF
    const float* tgt = (const float*)d_in[1];   // (B,3) geodetic lat/lon/h
    float* out = (float*)d_out;
    long B = (long)in_sizes[0] / 3;

    float* blockmax = (float*)((char*)d_ws + PART_OFF);
    double* partials = (double*)((char*)d_ws + PART2_OFF);

    long coop_cap = (long)GRID * GPB_MAX * 4;
    if (B <= coop_cap) {
        void* args[] = { (void*)&inp, (void*)&tgt, (void*)&blockmax,
                         (void*)&partials, (void*)&out, (void*)&B };
        hipLaunchCooperativeKernel((const void*)k_fused, dim3(GRID), dim3(THREADS),
                                   args, 0, stream);
    } else {
        // fallback: proven R4 4-kernel pipeline
        float* maxslot = (float*)d_ws;
        double* partials2 = (double*)((char*)d_ws + PART2_OFF);
        float* dist_arr = nullptr;
        size_t need = (size_t)DIST_OFF + (size_t)B * sizeof(float);
        if (ws_size >= need) dist_arr = (float*)((char*)d_ws + DIST_OFF);
        long ngroups = (B + 3) >> 2;
        int nblocks = (int)((ngroups + THREADS - 1) / THREADS);
        if (nblocks > PART_CAP) nblocks = PART_CAP;
        if (nblocks < 1) nblocks = 1;
        k_pass1<<<nblocks, THREADS, 0, stream>>>(inp, tgt, dist_arr, blockmax, B);
        k_max<<<1, THREADS, 0, stream>>>(blockmax, nblocks, maxslot);
        k_pass2<<<nblocks, THREADS, 0, stream>>>(dist_arr, inp, tgt, maxslot, partials2, B);
        k_final<<<1, THREADS, 0, stream>>>(partials2, nblocks, out, B);
    }
}

// Round 6
// 136.932 us; speedup vs baseline: 1.7584x; 1.7584x over previous
//
#include <hip/hip_runtime.h>
#include <math.h>

// ---------------------------------------------------------------------------
// FocalLoss: geodetic->ECEF->ENU error -> distance -> focal-weighted RMS.
// 3-kernel pipeline: pass1 (dist -> d_ws, per-block max) ->
// pass2 (fold blockmax inline + focal + per-block partial) -> final.
//
// R5 post-mortem: fused coop kernel regressed (occupancy 22%, VGPR 52 =
// compiler serialized the 4 indep chains under the 128-reg cap).
// R6: back to R4's multi-kernel shape; pass1 rewritten BREADTH-FIRST
// (sincos8 carries all 8 angles through reduction + both Horner ladders as
// 8-wide unrolled stages) so ILP survives the scheduler; launch_bounds(256,3)
// to allow ~170 VGPRs; k_max folded into pass2 (each block folds blockmax,
// L2-hot); no atomics anywhere.
// ---------------------------------------------------------------------------

#define THREADS 256
#define PART_CAP 8192
#define BMAX_OFF 64
#define PART_OFF (64 + PART_CAP * 4)                 // doubles, 8-aligned
#define DIST_OFF (1 << 20)                           // 1 MB, 16B-aligned

// ---- 8-wide breadth-first double sincos, |x| <= ~3.15 (no Payne-Hanek) ----
// fdlibm minimax coefficients; abs err ~1e-16 -> ~1e-9 m at N=6.4e6.
__device__ __forceinline__ void sincos8(const double* __restrict__ x,
                                        double* __restrict__ s,
                                        double* __restrict__ c) {
    const double TWO_OVER_PI = 0.636619772367581343076;
    const double PIO2_HI = 1.57079632679489655800e+00;
    const double PIO2_LO = 6.12323399573676603587e-17;

    double kd[8], r[8], r2[8];
    int q[8];
#pragma unroll
    for (int j = 0; j < 8; ++j) {
        kd[j] = rint(x[j] * TWO_OVER_PI);
        q[j] = ((int)kd[j]) & 3;
    }
#pragma unroll
    for (int j = 0; j < 8; ++j) {
        double rr = fma(-kd[j], PIO2_HI, x[j]);
        r[j] = fma(-kd[j], PIO2_LO, rr);
        r2[j] = r[j] * r[j];
    }
    double ps[8], pc[8];
#pragma unroll
    for (int j = 0; j < 8; ++j) { ps[j] = 1.58969099521155010221e-10;
                                  pc[j] = -1.13596475577881948265e-11; }
#pragma unroll
    for (int j = 0; j < 8; ++j) { ps[j] = fma(ps[j], r2[j], -2.50507602534068634195e-08);
                                  pc[j] = fma(pc[j], r2[j],  2.08757232129817482790e-09); }
#pragma unroll
    for (int j = 0; j < 8; ++j) { ps[j] = fma(ps[j], r2[j],  2.75573137070700676789e-06);
                                  pc[j] = fma(pc[j], r2[j], -2.75573143513906633035e-07); }
#pragma unroll
    for (int j = 0; j < 8; ++j) { ps[j] = fma(ps[j], r2[j], -1.98412698298579493134e-04);
                                  pc[j] = fma(pc[j], r2[j],  2.48015872894767294178e-05); }
#pragma unroll
    for (int j = 0; j < 8; ++j) { ps[j] = fma(ps[j], r2[j],  8.33333333332248946124e-03);
                                  pc[j] = fma(pc[j], r2[j], -1.38888888888741095749e-03); }
#pragma unroll
    for (int j = 0; j < 8; ++j) { ps[j] = fma(ps[j], r2[j], -1.66666666666666324348e-01);
                                  pc[j] = fma(pc[j], r2[j],  4.16666666666666019037e-02); }
#pragma unroll
    for (int j = 0; j < 8; ++j) {
        double sv = fma(r2[j] * r[j], ps[j], r[j]);
        double cv = fma(r2[j] * r2[j], pc[j], fma(-0.5, r2[j], 1.0));
        double sr = (q[j] & 1) ? cv : sv;
        double cr = (q[j] & 1) ? sv : cv;
        s[j] = (q[j] & 2) ? -sr : sr;
        c[j] = ((q[j] + 1) & 2) ? -cr : cr;
    }
}

// ---- 4 elements, breadth-first through the shared sincos8 ----
__device__ __forceinline__ void dist_group4(const float* __restrict__ lat,
                                            const float* __restrict__ lon,
                                            const float* __restrict__ hh,
                                            const float* __restrict__ px,
                                            const float* __restrict__ py,
                                            const float* __restrict__ pz,
                                            float* __restrict__ dout) {
    const float D2R = (float)0.017453292519943295;   // fp32 deg2rad, matches numpy
    double x[8], s8[8], c8[8];
#pragma unroll
    for (int j = 0; j < 4; ++j) x[j] = (double)(lat[j] * D2R);
#pragma unroll
    for (int j = 0; j < 4; ++j) x[4 + j] = (double)(lon[j] * D2R);
    sincos8(x, s8, c8);

    const double A = 6378137.0, E2 = 0.00669437999014;
#pragma unroll
    for (int j = 0; j < 4; ++j) {
        double sl = s8[j], cl = c8[j], so = s8[4 + j], co = c8[4 + j];
        double h = (double)hh[j];
        double w = fma(-E2 * sl, sl, 1.0);            // [0.9933, 1]
        double y = fma(-0.5, w, 1.5);                 // rsqrt seed
        y = y * fma(-0.5 * w, y * y, 1.5);            // 2 Newton -> ~1e-19
        y = y * fma(-0.5 * w, y * y, 1.5);
        double N = A * y, Nh = N + h;
        double X = Nh * cl * co;
        double Y = Nh * cl * so;
        double Z = fma(N, -E2, N + h) * sl;           // (N*(1-E2)+h)*sl
        double dx = (double)px[j] - X;
        double dy = (double)py[j] - Y;
        double dz = (double)pz[j] - Z;
        double e = -so * dx + co * dy;
        double n = -sl * co * dx - sl * so * dy + cl * dz;
        double u =  cl * co * dx + cl * so * dy + sl * dz;
        dout[j] = sqrtf((float)(e * e + n * n + u * u));
    }
}

// scalar path for the tail
__device__ __forceinline__ float dist_one(float latd, float lond, float hf,
                                          float pxx, float pyy, float pzz) {
    float lat[4] = {latd, latd, latd, latd}, lon[4] = {lond, lond, lond, lond};
    float hh[4] = {hf, hf, hf, hf};
    float px[4] = {pxx, pxx, pxx, pxx}, py[4] = {pyy, pyy, pyy, pyy}, pz[4] = {pzz, pzz, pzz, pzz};
    float d[4];
    dist_group4(lat, lon, hh, px, py, pz, d);
    return d[0];
}

__global__ __launch_bounds__(THREADS, 3)
void k_pass1(const float* __restrict__ inp, const float* __restrict__ tgt,
             float* __restrict__ dist_arr, float* __restrict__ blockmax, long B) {
    long ngroups = (B + 3) >> 2;
    long gstride = (long)gridDim.x * blockDim.x;
    float lmax = 0.0f;
    for (long g = (long)blockIdx.x * blockDim.x + threadIdx.x; g < ngroups; g += gstride) {
        long base = g << 2;
        if (base + 3 < B) {
            const float4* t4 = (const float4*)(tgt + 3 * base);   // 48B, 16B-aligned
            float4 ta = t4[0], tb = t4[1], tc = t4[2];
            const float4* p4 = (const float4*)(inp + 3 * base);
            float4 pa = p4[0], pb = p4[1], pc = p4[2];
            float lat[4] = {ta.x, ta.w, tb.z, tc.y};
            float lon[4] = {ta.y, tb.x, tb.w, tc.z};
            float hh[4]  = {ta.z, tb.y, tc.x, tc.w};
            float px[4]  = {pa.x, pa.w, pb.z, pc.y};
            float py[4]  = {pa.y, pb.x, pb.w, pc.z};
            float pz[4]  = {pa.z, pb.y, pc.x, pc.w};
            float d[4];
            dist_group4(lat, lon, hh, px, py, pz, d);
            if (dist_arr) *(float4*)(dist_arr + base) = make_float4(d[0], d[1], d[2], d[3]);
            lmax = fmaxf(lmax, fmaxf(fmaxf(d[0], d[1]), fmaxf(d[2], d[3])));
        } else {
            for (long i = base; i < B; ++i) {
                float d = dist_one(tgt[3*i], tgt[3*i+1], tgt[3*i+2],
                                   inp[3*i], inp[3*i+1], inp[3*i+2]);
                if (dist_arr) dist_arr[i] = d;
                lmax = fmaxf(lmax, d);
            }
        }
    }
    for (int off = 32; off > 0; off >>= 1)
        lmax = fmaxf(lmax, __shfl_down(lmax, off, 64));
    __shared__ float smax[THREADS / 64];
    if ((threadIdx.x & 63) == 0) smax[threadIdx.x >> 6] = lmax;
    __syncthreads();
    if (threadIdx.x == 0) {
        float m = smax[0];
        for (int w = 1; w < THREADS / 64; ++w) m = fmaxf(m, smax[w]);
        blockmax[blockIdx.x] = m;
    }
}

__device__ __forceinline__ double focal2(float d, float denom) {
    float g = 2.0f * __expf(-d);                  // dynamic gamma (SCALE=1, GAMMA=2)
    float b = 1.0f - sqrtf(d / denom);            // true div: max elem ratio <= 1
    b = fmaxf(b, 0.0f);
    float wgt = __builtin_amdgcn_exp2f(g * __log2f(b));  // b^g; log2(0)->-inf->0 ok
    float fl = wgt * d;                           // ALPHA = 1
    return (double)fl * (double)fl;
}

__global__ void k_pass2(const float* __restrict__ dist_arr,
                        const float* __restrict__ inp,
                        const float* __restrict__ tgt,
                        const float* __restrict__ blockmax, int nb1,
                        double* __restrict__ partials, long B) {
    __shared__ float smax[THREADS / 64];
    __shared__ double sacc[THREADS / 64];
    __shared__ float sb;
    int tid = threadIdx.x;

    // fold blockmax inline (nb1 floats, L2-hot)
    float m = 0.0f;
    for (int i = tid; i < nb1; i += THREADS) m = fmaxf(m, blockmax[i]);
    for (int off = 32; off > 0; off >>= 1)
        m = fmaxf(m, __shfl_down(m, off, 64));
    if ((tid & 63) == 0) smax[tid >> 6] = m;
    __syncthreads();
    if (tid == 0) {
        float mm = smax[0];
        for (int w = 1; w < THREADS / 64; ++w) mm = fmaxf(mm, smax[w]);
        sb = mm;
    }
    __syncthreads();
    float denom = sb + 1e-8f;

    long ngroups = (B + 3) >> 2;
    long gstride = (long)gridDim.x * blockDim.x;
    double acc = 0.0;
    for (long g = (long)blockIdx.x * blockDim.x + tid; g < ngroups; g += gstride) {
        long base = g << 2;
        if (base + 3 < B) {
            float d0, d1, d2, d3;
            if (dist_arr) {
                float4 d4 = *(const float4*)(dist_arr + base);
                d0 = d4.x; d1 = d4.y; d2 = d4.z; d3 = d4.w;
            } else {
                const float4* t4 = (const float4*)(tgt + 3 * base);
                float4 ta = t4[0], tb = t4[1], tc = t4[2];
                const float4* p4 = (const float4*)(inp + 3 * base);
                float4 pa = p4[0], pb = p4[1], pc = p4[2];
                float lat[4] = {ta.x, ta.w, tb.z, tc.y};
                float lon[4] = {ta.y, tb.x, tb.w, tc.z};
                float hh[4]  = {ta.z, tb.y, tc.x, tc.w};
                float px[4]  = {pa.x, pa.w, pb.z, pc.y};
                float py[4]  = {pa.y, pb.x, pb.w, pc.z};
                float pz[4]  = {pa.z, pb.y, pc.x, pc.w};
                float d[4];
                dist_group4(lat, lon, hh, px, py, pz, d);
                d0 = d[0]; d1 = d[1]; d2 = d[2]; d3 = d[3];
            }
            acc += focal2(d0, denom) + focal2(d1, denom)
                 + focal2(d2, denom) + focal2(d3, denom);
        } else {
            for (long i = base; i < B; ++i) {
                float d = dist_arr ? dist_arr[i]
                                   : dist_one(tgt[3*i], tgt[3*i+1], tgt[3*i+2],
                                              inp[3*i], inp[3*i+1], inp[3*i+2]);
                acc += focal2(d, denom);
            }
        }
    }
    for (int off = 32; off > 0; off >>= 1)
        acc += __shfl_down(acc, off, 64);
    if ((tid & 63) == 0) sacc[tid >> 6] = acc;
    __syncthreads();
    if (tid == 0) {
        double s = sacc[0];
        for (int w = 1; w < THREADS / 64; ++w) s += sacc[w];
        partials[blockIdx.x] = s;
    }
}

__global__ void k_final(const double* __restrict__ partials, int nparts,
                        float* __restrict__ out, long B) {
    double acc = 0.0;
    for (int i = threadIdx.x; i < nparts; i += blockDim.x) acc += partials[i];
    for (int off = 32; off > 0; off >>= 1)
        acc += __shfl_down(acc, off, 64);
    __shared__ double lds[THREADS / 64];
    if ((threadIdx.x & 63) == 0) lds[threadIdx.x >> 6] = acc;
    __syncthreads();
    if (threadIdx.x == 0) {
        double s = lds[0];
        for (int w = 1; w < THREADS / 64; ++w) s += lds[w];
        out[0] = (float)sqrt(s / (double)B);
    }
}

extern "C" void kernel_launch(void* const* d_in, const int* in_sizes, int n_in,
                              void* d_out, int out_size, void* d_ws, size_t ws_size,
                              hipStream_t stream) {
    const float* inp = (const float*)d_in[0];   // (B,3) predicted ECEF
    const float* tgt = (const float*)d_in[1];   // (B,3) geodetic lat/lon/h
    float* out = (float*)d_out;
    long B = (long)in_sizes[0] / 3;

    float* blockmax = (float*)((char*)d_ws + BMAX_OFF);
    double* partials = (double*)((char*)d_ws + PART_OFF);
    float* dist_arr = nullptr;
    size_t need = (size_t)DIST_OFF + (size_t)B * sizeof(float);
    if (ws_size >= need) dist_arr = (float*)((char*)d_ws + DIST_OFF);

    long ngroups = (B + 3) >> 2;
    int nblocks = (int)((ngroups + THREADS - 1) / THREADS);
    if (nblocks > PART_CAP) nblocks = PART_CAP;
    if (nblocks < 1) nblocks = 1;

    k_pass1<<<nblocks, THREADS, 0, stream>>>(inp, tgt, dist_arr, blockmax, B);
    k_pass2<<<nblocks, THREADS, 0, stream>>>(dist_arr, inp, tgt, blockmax, nblocks, partials, B);
    k_final<<<1, THREADS, 0, stream>>>(partials, nblocks, out, B);
}

// Round 8
// 135.377 us; speedup vs baseline: 1.7786x; 1.0115x over previous
//
#include <hip/hip_runtime.h>
#include <math.h>

// ---------------------------------------------------------------------------
// FocalLoss: geodetic->ECEF->ENU error -> distance -> focal-weighted RMS.
// 3-kernel pipeline: pass1 (dist -> d_ws, per-block max) ->
// pass2 (fold blockmax inline + focal + per-block partial) -> final.
//
// R8 = R6 structure (proven passing) + R7's two safe algebraic deltas:
//  - ENU rotation REMOVED: the ENU rows are an orthonormal basis, so
//    |ENU(d)| == |d| exactly; we computed the rotation in f64 so the dist
//    changes by <1e-9 m. Deletes ~15 f64 FMAs/elem + the chain tail.
//  - Horner ladders trimmed one term (residual ~7e-12 -> 4e-5 m, harmless).
// R7's 8-elem/thread + changed grid arithmetic caused an HSA abort; reverted
// wholesale to isolate variables (R9 may retry it alone).
// ---------------------------------------------------------------------------

#define THREADS 256
#define PART_CAP 8192
#define BMAX_OFF 64
#define PART_OFF (64 + PART_CAP * 4)                 // doubles, 8-aligned
#define DIST_OFF (1 << 20)                           // 1 MB, 16B-aligned

// ---- 8-wide breadth-first double sincos, |x| <= ~3.15 (no Payne-Hanek) ----
// fdlibm minimax, one term trimmed: abs err ~7e-12 -> 4e-5 m at N=6.4e6.
__device__ __forceinline__ void sincos8(const double* __restrict__ x,
                                        double* __restrict__ s,
                                        double* __restrict__ c) {
    const double TWO_OVER_PI = 0.636619772367581343076;
    const double PIO2_HI = 1.57079632679489655800e+00;
    const double PIO2_LO = 6.12323399573676603587e-17;

    double kd[8], r[8], r2[8];
    int q[8];
#pragma unroll
    for (int j = 0; j < 8; ++j) {
        kd[j] = rint(x[j] * TWO_OVER_PI);
        q[j] = ((int)kd[j]) & 3;
    }
#pragma unroll
    for (int j = 0; j < 8; ++j) {
        double rr = fma(-kd[j], PIO2_HI, x[j]);
        r[j] = fma(-kd[j], PIO2_LO, rr);
        r2[j] = r[j] * r[j];
    }
    double ps[8], pc[8];
#pragma unroll
    for (int j = 0; j < 8; ++j) { ps[j] = -2.50507602534068634195e-08;
                                  pc[j] =  2.08757232129817482790e-09; }
#pragma unroll
    for (int j = 0; j < 8; ++j) { ps[j] = fma(ps[j], r2[j],  2.75573137070700676789e-06);
                                  pc[j] = fma(pc[j], r2[j], -2.75573143513906633035e-07); }
#pragma unroll
    for (int j = 0; j < 8; ++j) { ps[j] = fma(ps[j], r2[j], -1.98412698298579493134e-04);
                                  pc[j] = fma(pc[j], r2[j],  2.48015872894767294178e-05); }
#pragma unroll
    for (int j = 0; j < 8; ++j) { ps[j] = fma(ps[j], r2[j],  8.33333333332248946124e-03);
                                  pc[j] = fma(pc[j], r2[j], -1.38888888888741095749e-03); }
#pragma unroll
    for (int j = 0; j < 8; ++j) { ps[j] = fma(ps[j], r2[j], -1.66666666666666324348e-01);
                                  pc[j] = fma(pc[j], r2[j],  4.16666666666666019037e-02); }
#pragma unroll
    for (int j = 0; j < 8; ++j) {
        double sv = fma(r2[j] * r[j], ps[j], r[j]);
        double cv = fma(r2[j] * r2[j], pc[j], fma(-0.5, r2[j], 1.0));
        double sr = (q[j] & 1) ? cv : sv;
        double cr = (q[j] & 1) ? sv : cv;
        s[j] = (q[j] & 2) ? -sr : sr;
        c[j] = ((q[j] + 1) & 2) ? -cr : cr;
    }
}

// ---- 4 elements, breadth-first sincos, NO rotation (|R d| == |d|) ----
__device__ __forceinline__ void dist_group4(const float* __restrict__ lat,
                                            const float* __restrict__ lon,
                                            const float* __restrict__ hh,
                                            const float* __restrict__ px,
                                            const float* __restrict__ py,
                                            const float* __restrict__ pz,
                                            float* __restrict__ dout) {
    const float D2R = (float)0.017453292519943295;   // fp32 deg2rad, matches numpy
    double x[8], s8[8], c8[8];
#pragma unroll
    for (int j = 0; j < 4; ++j) x[j] = (double)(lat[j] * D2R);
#pragma unroll
    for (int j = 0; j < 4; ++j) x[4 + j] = (double)(lon[j] * D2R);
    sincos8(x, s8, c8);

    const double A = 6378137.0, E2 = 0.00669437999014;
#pragma unroll
    for (int j = 0; j < 4; ++j) {
        double sl = s8[j], cl = c8[j], so = s8[4 + j], co = c8[4 + j];
        double h = (double)hh[j];
        double w = fma(-E2 * sl, sl, 1.0);            // [0.9933, 1]
        double y = fma(-0.5, w, 1.5);                 // rsqrt seed
        y = y * fma(-0.5 * w, y * y, 1.5);            // 2 Newton -> ~1e-19
        y = y * fma(-0.5 * w, y * y, 1.5);
        double N = A * y, Nh = N + h;
        double X = Nh * cl * co;
        double Y = Nh * cl * so;
        double Z = fma(N, -E2, N + h) * sl;           // (N*(1-E2)+h)*sl
        double dx = (double)px[j] - X;
        double dy = (double)py[j] - Y;
        double dz = (double)pz[j] - Z;
        dout[j] = sqrtf((float)(dx * dx + dy * dy + dz * dz));
    }
}

// scalar path for the tail
__device__ __forceinline__ float dist_one(float latd, float lond, float hf,
                                          float pxx, float pyy, float pzz) {
    float lat[4] = {latd, latd, latd, latd}, lon[4] = {lond, lond, lond, lond};
    float hh[4] = {hf, hf, hf, hf};
    float px[4] = {pxx, pxx, pxx, pxx}, py[4] = {pyy, pyy, pyy, pyy}, pz[4] = {pzz, pzz, pzz, pzz};
    float d[4];
    dist_group4(lat, lon, hh, px, py, pz, d);
    return d[0];
}

__global__ __launch_bounds__(THREADS, 3)
void k_pass1(const float* __restrict__ inp, const float* __restrict__ tgt,
             float* __restrict__ dist_arr, float* __restrict__ blockmax, long B) {
    long ngroups = (B + 3) >> 2;
    long gstride = (long)gridDim.x * blockDim.x;
    float lmax = 0.0f;
    for (long g = (long)blockIdx.x * blockDim.x + threadIdx.x; g < ngroups; g += gstride) {
        long base = g << 2;
        if (base + 3 < B) {
            const float4* t4 = (const float4*)(tgt + 3 * base);   // 48B, 16B-aligned
            float4 ta = t4[0], tb = t4[1], tc = t4[2];
            const float4* p4 = (const float4*)(inp + 3 * base);
            float4 pa = p4[0], pb = p4[1], pc = p4[2];
            float lat[4] = {ta.x, ta.w, tb.z, tc.y};
            float lon[4] = {ta.y, tb.x, tb.w, tc.z};
            float hh[4]  = {ta.z, tb.y, tc.x, tc.w};
            float px[4]  = {pa.x, pa.w, pb.z, pc.y};
            float py[4]  = {pa.y, pb.x, pb.w, pc.z};
            float pz[4]  = {pa.z, pb.y, pc.x, pc.w};
            float d[4];
            dist_group4(lat, lon, hh, px, py, pz, d);
            if (dist_arr) *(float4*)(dist_arr + base) = make_float4(d[0], d[1], d[2], d[3]);
            lmax = fmaxf(lmax, fmaxf(fmaxf(d[0], d[1]), fmaxf(d[2], d[3])));
        } else {
            for (long i = base; i < B; ++i) {
                float d = dist_one(tgt[3*i], tgt[3*i+1], tgt[3*i+2],
                                   inp[3*i], inp[3*i+1], inp[3*i+2]);
                if (dist_arr) dist_arr[i] = d;
                lmax = fmaxf(lmax, d);
            }
        }
    }
    for (int off = 32; off > 0; off >>= 1)
        lmax = fmaxf(lmax, __shfl_down(lmax, off, 64));
    __shared__ float smax[THREADS / 64];
    if ((threadIdx.x & 63) == 0) smax[threadIdx.x >> 6] = lmax;
    __syncthreads();
    if (threadIdx.x == 0) {
        float m = smax[0];
        for (int w = 1; w < THREADS / 64; ++w) m = fmaxf(m, smax[w]);
        blockmax[blockIdx.x] = m;
    }
}

__device__ __forceinline__ double focal2(float d, float denom) {
    float g = 2.0f * __expf(-d);                  // dynamic gamma (SCALE=1, GAMMA=2)
    float b = 1.0f - sqrtf(d / denom);            // true div: max elem ratio <= 1
    b = fmaxf(b, 0.0f);
    float wgt = __builtin_amdgcn_exp2f(g * __log2f(b));  // b^g; log2(0)->-inf->0 ok
    float fl = wgt * d;                           // ALPHA = 1
    return (double)fl * (double)fl;
}

__global__ void k_pass2(const float* __restrict__ dist_arr,
                        const float* __restrict__ inp,
                        const float* __restrict__ tgt,
                        const float* __restrict__ blockmax, int nb1,
                        double* __restrict__ partials, long B) {
    __shared__ float smax[THREADS / 64];
    __shared__ double sacc[THREADS / 64];
    __shared__ float sb;
    int tid = threadIdx.x;

    // fold blockmax inline (nb1 floats, L2-hot)
    float m = 0.0f;
    for (int i = tid; i < nb1; i += THREADS) m = fmaxf(m, blockmax[i]);
    for (int off = 32; off > 0; off >>= 1)
        m = fmaxf(m, __shfl_down(m, off, 64));
    if ((tid & 63) == 0) smax[tid >> 6] = m;
    __syncthreads();
    if (tid == 0) {
        float mm = smax[0];
        for (int w = 1; w < THREADS / 64; ++w) mm = fmaxf(mm, smax[w]);
        sb = mm;
    }
    __syncthreads();
    float denom = sb + 1e-8f;

    long ngroups = (B + 3) >> 2;
    long gstride = (long)gridDim.x * blockDim.x;
    double acc = 0.0;
    for (long g = (long)blockIdx.x * blockDim.x + tid; g < ngroups; g += gstride) {
        long base = g << 2;
        if (base + 3 < B) {
            float d0, d1, d2, d3;
            if (dist_arr) {
                float4 d4 = *(const float4*)(dist_arr + base);
                d0 = d4.x; d1 = d4.y; d2 = d4.z; d3 = d4.w;
            } else {
                const float4* t4 = (const float4*)(tgt + 3 * base);
                float4 ta = t4[0], tb = t4[1], tc = t4[2];
                const float4* p4 = (const float4*)(inp + 3 * base);
                float4 pa = p4[0], pb = p4[1], pc = p4[2];
                float lat[4] = {ta.x, ta.w, tb.z, tc.y};
                float lon[4] = {ta.y, tb.x, tb.w, tc.z};
                float hh[4]  = {ta.z, tb.y, tc.x, tc.w};
                float px[4]  = {pa.x, pa.w, pb.z, pc.y};
                float py[4]  = {pa.y, pb.x, pb.w, pc.z};
                float pz[4]  = {pa.z, pb.y, pc.x, pc.w};
                float d[4];
                dist_group4(lat, lon, hh, px, py, pz, d);
                d0 = d[0]; d1 = d[1]; d2 = d[2]; d3 = d[3];
            }
            acc += focal2(d0, denom) + focal2(d1, denom)
                 + focal2(d2, denom) + focal2(d3, denom);
        } else {
            for (long i = base; i < B; ++i) {
                float d = dist_arr ? dist_arr[i]
                                   : dist_one(tgt[3*i], tgt[3*i+1], tgt[3*i+2],
                                              inp[3*i], inp[3*i+1], inp[3*i+2]);
                acc += focal2(d, denom);
            }
        }
    }
    for (int off = 32; off > 0; off >>= 1)
        acc += __shfl_down(acc, off, 64);
    if ((tid & 63) == 0) sacc[tid >> 6] = acc;
    __syncthreads();
    if (tid == 0) {
        double s = sacc[0];
        for (int w = 1; w < THREADS / 64; ++w) s += sacc[w];
        partials[blockIdx.x] = s;
    }
}

__global__ void k_final(const double* __restrict__ partials, int nparts,
                        float* __restrict__ out, long B) {
    double acc = 0.0;
    for (int i = threadIdx.x; i < nparts; i += blockDim.x) acc += partials[i];
    for (int off = 32; off > 0; off >>= 1)
        acc += __shfl_down(acc, off, 64);
    __shared__ double lds[THREADS / 64];
    if ((threadIdx.x & 63) == 0) lds[threadIdx.x >> 6] = acc;
    __syncthreads();
    if (threadIdx.x == 0) {
        double s = lds[0];
        for (int w = 1; w < THREADS / 64; ++w) s += lds[w];
        out[0] = (float)sqrt(s / (double)B);
    }
}

extern "C" void kernel_launch(void* const* d_in, const int* in_sizes, int n_in,
                              void* d_out, int out_size, void* d_ws, size_t ws_size,
                              hipStream_t stream) {
    const float* inp = (const float*)d_in[0];   // (B,3) predicted ECEF
    const float* tgt = (const float*)d_in[1];   // (B,3) geodetic lat/lon/h
    float* out = (float*)d_out;
    long B = (long)in_sizes[0] / 3;

    float* blockmax = (float*)((char*)d_ws + BMAX_OFF);
    double* partials = (double*)((char*)d_ws + PART_OFF);
    float* dist_arr = nullptr;
    size_t need = (size_t)DIST_OFF + (size_t)B * sizeof(float);
    if (ws_size >= need) dist_arr = (float*)((char*)d_ws + DIST_OFF);

    long ngroups = (B + 3) >> 2;
    int nblocks = (int)((ngroups + THREADS - 1) / THREADS);
    if (nblocks > PART_CAP) nblocks = PART_CAP;
    if (nblocks < 1) nblocks = 1;

    k_pass1<<<nblocks, THREADS, 0, stream>>>(inp, tgt, dist_arr, blockmax, B);
    k_pass2<<<nblocks, THREADS, 0, stream>>>(dist_arr, inp, tgt, blockmax, nblocks, partials, B);
    k_final<<<1, THREADS, 0, stream>>>(partials, nblocks, out, B);
}

// Round 9
// 133.020 us; speedup vs baseline: 1.8101x; 1.0177x over previous
//
#include <hip/hip_runtime.h>
#include <math.h>

// ---------------------------------------------------------------------------
// FocalLoss: geodetic->ECEF->ENU error -> distance -> focal-weighted RMS.
// 3-kernel pipeline: pass1 (dist -> d_ws, per-block max) ->
// pass2 (fold blockmax inline + focal + per-block partial) -> final.
//
// R9: pass1 processes TWO stride-separated groups per thread with all 12
// float4 loads hoisted ahead of compute (2x memory-level parallelism).
// Rationale: R4/R6/R8 plateau at ~135us total despite ~35% f64-op delta ->
// pass1 (~36us vs 18us BW floor) is latency-bound with 1 group/thread.
// Addressing per group is byte-identical to the proven R8 code.
// ---------------------------------------------------------------------------

#define THREADS 256
#define PART_CAP 8192
#define BMAX_OFF 64
#define PART_OFF (64 + PART_CAP * 4)                 // doubles, 8-aligned
#define DIST_OFF (1 << 20)                           // 1 MB, 16B-aligned

// ---- 8-wide breadth-first double sincos, |x| <= ~3.15 (no Payne-Hanek) ----
// fdlibm minimax, one term trimmed: abs err ~7e-12 -> 4e-5 m at N=6.4e6.
__device__ __forceinline__ void sincos8(const double* __restrict__ x,
                                        double* __restrict__ s,
                                        double* __restrict__ c) {
    const double TWO_OVER_PI = 0.636619772367581343076;
    const double PIO2_HI = 1.57079632679489655800e+00;
    const double PIO2_LO = 6.12323399573676603587e-17;

    double kd[8], r[8], r2[8];
    int q[8];
#pragma unroll
    for (int j = 0; j < 8; ++j) {
        kd[j] = rint(x[j] * TWO_OVER_PI);
        q[j] = ((int)kd[j]) & 3;
    }
#pragma unroll
    for (int j = 0; j < 8; ++j) {
        double rr = fma(-kd[j], PIO2_HI, x[j]);
        r[j] = fma(-kd[j], PIO2_LO, rr);
        r2[j] = r[j] * r[j];
    }
    double ps[8], pc[8];
#pragma unroll
    for (int j = 0; j < 8; ++j) { ps[j] = -2.50507602534068634195e-08;
                                  pc[j] =  2.08757232129817482790e-09; }
#pragma unroll
    for (int j = 0; j < 8; ++j) { ps[j] = fma(ps[j], r2[j],  2.75573137070700676789e-06);
                                  pc[j] = fma(pc[j], r2[j], -2.75573143513906633035e-07); }
#pragma unroll
    for (int j = 0; j < 8; ++j) { ps[j] = fma(ps[j], r2[j], -1.98412698298579493134e-04);
                                  pc[j] = fma(pc[j], r2[j],  2.48015872894767294178e-05); }
#pragma unroll
    for (int j = 0; j < 8; ++j) { ps[j] = fma(ps[j], r2[j],  8.33333333332248946124e-03);
                                  pc[j] = fma(pc[j], r2[j], -1.38888888888741095749e-03); }
#pragma unroll
    for (int j = 0; j < 8; ++j) { ps[j] = fma(ps[j], r2[j], -1.66666666666666324348e-01);
                                  pc[j] = fma(pc[j], r2[j],  4.16666666666666019037e-02); }
#pragma unroll
    for (int j = 0; j < 8; ++j) {
        double sv = fma(r2[j] * r[j], ps[j], r[j]);
        double cv = fma(r2[j] * r2[j], pc[j], fma(-0.5, r2[j], 1.0));
        double sr = (q[j] & 1) ? cv : sv;
        double cr = (q[j] & 1) ? sv : cv;
        s[j] = (q[j] & 2) ? -sr : sr;
        c[j] = ((q[j] + 1) & 2) ? -cr : cr;
    }
}

// ---- 4 elements, breadth-first sincos, NO rotation (|R d| == |d|) ----
__device__ __forceinline__ void dist_group4(const float* __restrict__ lat,
                                            const float* __restrict__ lon,
                                            const float* __restrict__ hh,
                                            const float* __restrict__ px,
                                            const float* __restrict__ py,
                                            const float* __restrict__ pz,
                                            float* __restrict__ dout) {
    const float D2R = (float)0.017453292519943295;   // fp32 deg2rad, matches numpy
    double x[8], s8[8], c8[8];
#pragma unroll
    for (int j = 0; j < 4; ++j) x[j] = (double)(lat[j] * D2R);
#pragma unroll
    for (int j = 0; j < 4; ++j) x[4 + j] = (double)(lon[j] * D2R);
    sincos8(x, s8, c8);

    const double A = 6378137.0, E2 = 0.00669437999014;
#pragma unroll
    for (int j = 0; j < 4; ++j) {
        double sl = s8[j], cl = c8[j], so = s8[4 + j], co = c8[4 + j];
        double h = (double)hh[j];
        double w = fma(-E2 * sl, sl, 1.0);            // [0.9933, 1]
        double y = fma(-0.5, w, 1.5);                 // rsqrt seed
        y = y * fma(-0.5 * w, y * y, 1.5);            // 2 Newton -> ~1e-19
        y = y * fma(-0.5 * w, y * y, 1.5);
        double N = A * y, Nh = N + h;
        double X = Nh * cl * co;
        double Y = Nh * cl * so;
        double Z = fma(N, -E2, N + h) * sl;           // (N*(1-E2)+h)*sl
        double dx = (double)px[j] - X;
        double dy = (double)py[j] - Y;
        double dz = (double)pz[j] - Z;
        dout[j] = sqrtf((float)(dx * dx + dy * dy + dz * dz));
    }
}

// scalar path for the tail
__device__ __forceinline__ float dist_one(float latd, float lond, float hf,
                                          float pxx, float pyy, float pzz) {
    float lat[4] = {latd, latd, latd, latd}, lon[4] = {lond, lond, lond, lond};
    float hh[4] = {hf, hf, hf, hf};
    float px[4] = {pxx, pxx, pxx, pxx}, py[4] = {pyy, pyy, pyy, pyy}, pz[4] = {pzz, pzz, pzz, pzz};
    float d[4];
    dist_group4(lat, lon, hh, px, py, pz, d);
    return d[0];
}

#define UNPACK4(ta, tb, tc, lat, lon, hh)                         \
    float lat[4] = {ta.x, ta.w, tb.z, tc.y};                      \
    float lon[4] = {ta.y, tb.x, tb.w, tc.z};                      \
    float hh[4]  = {ta.z, tb.y, tc.x, tc.w};

__global__ __launch_bounds__(THREADS, 2)
void k_pass1(const float* __restrict__ inp, const float* __restrict__ tgt,
             float* __restrict__ dist_arr, float* __restrict__ blockmax, long B) {
    long ngroups = (B + 3) >> 2;
    long nthreads = (long)gridDim.x * blockDim.x;     // = half of ngroups (rounded up)
    long gstride = 2 * nthreads;
    float lmax = 0.0f;
    for (long g = (long)blockIdx.x * blockDim.x + threadIdx.x; g < ngroups; g += gstride) {
        long gA = g;
        long gB = g + nthreads;                       // stride-separated partner group
        long baseA = gA << 2;
        long baseB = gB << 2;
        bool fastA = (baseA + 3 < B);
        bool fastB = (gB < ngroups) && (baseB + 3 < B);

        if (fastA && fastB) {
            // hoist ALL 12 loads before any compute (2x outstanding loads)
            const float4* tA = (const float4*)(tgt + 3 * baseA);
            const float4* pA = (const float4*)(inp + 3 * baseA);
            const float4* tB = (const float4*)(tgt + 3 * baseB);
            const float4* pB = (const float4*)(inp + 3 * baseB);
            float4 ta0 = tA[0], ta1 = tA[1], ta2 = tA[2];
            float4 pa0 = pA[0], pa1 = pA[1], pa2 = pA[2];
            float4 tb0 = tB[0], tb1 = tB[1], tb2 = tB[2];
            float4 pb0 = pB[0], pb1 = pB[1], pb2 = pB[2];

            UNPACK4(ta0, ta1, ta2, latA, lonA, hhA);
            UNPACK4(pa0, pa1, pa2, pxA, pyA, pzA);
            float dA[4];
            dist_group4(latA, lonA, hhA, pxA, pyA, pzA, dA);

            UNPACK4(tb0, tb1, tb2, latB, lonB, hhB);
            UNPACK4(pb0, pb1, pb2, pxB, pyB, pzB);
            float dB[4];
            dist_group4(latB, lonB, hhB, pxB, pyB, pzB, dB);

            if (dist_arr) {
                *(float4*)(dist_arr + baseA) = make_float4(dA[0], dA[1], dA[2], dA[3]);
                *(float4*)(dist_arr + baseB) = make_float4(dB[0], dB[1], dB[2], dB[3]);
            }
            lmax = fmaxf(lmax, fmaxf(fmaxf(dA[0], dA[1]), fmaxf(dA[2], dA[3])));
            lmax = fmaxf(lmax, fmaxf(fmaxf(dB[0], dB[1]), fmaxf(dB[2], dB[3])));
        } else {
            // slow path: handle each group scalar-safe
            for (int pass = 0; pass < 2; ++pass) {
                long gg = pass ? gB : gA;
                if (gg >= ngroups) continue;
                long base = gg << 2;
                long end = base + 4 < B ? base + 4 : B;
                for (long i = base; i < end; ++i) {
                    float d = dist_one(tgt[3*i], tgt[3*i+1], tgt[3*i+2],
                                       inp[3*i], inp[3*i+1], inp[3*i+2]);
                    if (dist_arr) dist_arr[i] = d;
                    lmax = fmaxf(lmax, d);
                }
            }
        }
    }
    for (int off = 32; off > 0; off >>= 1)
        lmax = fmaxf(lmax, __shfl_down(lmax, off, 64));
    __shared__ float smax[THREADS / 64];
    if ((threadIdx.x & 63) == 0) smax[threadIdx.x >> 6] = lmax;
    __syncthreads();
    if (threadIdx.x == 0) {
        float m = smax[0];
        for (int w = 1; w < THREADS / 64; ++w) m = fmaxf(m, smax[w]);
        blockmax[blockIdx.x] = m;
    }
}

__device__ __forceinline__ double focal2(float d, float denom) {
    float g = 2.0f * __expf(-d);                  // dynamic gamma (SCALE=1, GAMMA=2)
    float b = 1.0f - sqrtf(d / denom);            // true div: max elem ratio <= 1
    b = fmaxf(b, 0.0f);
    float wgt = __builtin_amdgcn_exp2f(g * __log2f(b));  // b^g; log2(0)->-inf->0 ok
    float fl = wgt * d;                           // ALPHA = 1
    return (double)fl * (double)fl;
}

__global__ void k_pass2(const float* __restrict__ dist_arr,
                        const float* __restrict__ inp,
                        const float* __restrict__ tgt,
                        const float* __restrict__ blockmax, int nb1,
                        double* __restrict__ partials, long B) {
    __shared__ float smax[THREADS / 64];
    __shared__ double sacc[THREADS / 64];
    __shared__ float sb;
    int tid = threadIdx.x;

    // fold blockmax inline (nb1 floats, L2-hot)
    float m = 0.0f;
    for (int i = tid; i < nb1; i += THREADS) m = fmaxf(m, blockmax[i]);
    for (int off = 32; off > 0; off >>= 1)
        m = fmaxf(m, __shfl_down(m, off, 64));
    if ((tid & 63) == 0) smax[tid >> 6] = m;
    __syncthreads();
    if (tid == 0) {
        float mm = smax[0];
        for (int w = 1; w < THREADS / 64; ++w) mm = fmaxf(mm, smax[w]);
        sb = mm;
    }
    __syncthreads();
    float denom = sb + 1e-8f;

    long ngroups = (B + 3) >> 2;
    long gstride = (long)gridDim.x * blockDim.x;
    double acc = 0.0;
    for (long g = (long)blockIdx.x * blockDim.x + tid; g < ngroups; g += gstride) {
        long base = g << 2;
        if (base + 3 < B) {
            float d0, d1, d2, d3;
            if (dist_arr) {
                float4 d4 = *(const float4*)(dist_arr + base);
                d0 = d4.x; d1 = d4.y; d2 = d4.z; d3 = d4.w;
            } else {
                const float4* t4 = (const float4*)(tgt + 3 * base);
                float4 ta = t4[0], tb = t4[1], tc = t4[2];
                const float4* p4 = (const float4*)(inp + 3 * base);
                float4 pa = p4[0], pb = p4[1], pc = p4[2];
                UNPACK4(ta, tb, tc, lat, lon, hh);
                UNPACK4(pa, pb, pc, px, py, pz);
                float d[4];
                dist_group4(lat, lon, hh, px, py, pz, d);
                d0 = d[0]; d1 = d[1]; d2 = d[2]; d3 = d[3];
            }
            acc += focal2(d0, denom) + focal2(d1, denom)
                 + focal2(d2, denom) + focal2(d3, denom);
        } else {
            for (long i = base; i < B; ++i) {
                float d = dist_arr ? dist_arr[i]
                                   : dist_one(tgt[3*i], tgt[3*i+1], tgt[3*i+2],
                                              inp[3*i], inp[3*i+1], inp[3*i+2]);
                acc += focal2(d, denom);
            }
        }
    }
    for (int off = 32; off > 0; off >>= 1)
        acc += __shfl_down(acc, off, 64);
    if ((tid & 63) == 0) sacc[tid >> 6] = acc;
    __syncthreads();
    if (tid == 0) {
        double s = sacc[0];
        for (int w = 1; w < THREADS / 64; ++w) s += sacc[w];
        partials[blockIdx.x] = s;
    }
}

__global__ void k_final(const double* __restrict__ partials, int nparts,
                        float* __restrict__ out, long B) {
    double acc = 0.0;
    for (int i = threadIdx.x; i < nparts; i += blockDim.x) acc += partials[i];
    for (int off = 32; off > 0; off >>= 1)
        acc += __shfl_down(acc, off, 64);
    __shared__ double lds[THREADS / 64];
    if ((threadIdx.x & 63) == 0) lds[threadIdx.x >> 6] = acc;
    __syncthreads();
    if (threadIdx.x == 0) {
        double s = lds[0];
        for (int w = 1; w < THREADS / 64; ++w) s += lds[w];
        out[0] = (float)sqrt(s / (double)B);
    }
}

extern "C" void kernel_launch(void* const* d_in, const int* in_sizes, int n_in,
                              void* d_out, int out_size, void* d_ws, size_t ws_size,
                              hipStream_t stream) {
    const float* inp = (const float*)d_in[0];   // (B,3) predicted ECEF
    const float* tgt = (const float*)d_in[1];   // (B,3) geodetic lat/lon/h
    float* out = (float*)d_out;
    long B = (long)in_sizes[0] / 3;

    float* blockmax = (float*)((char*)d_ws + BMAX_OFF);
    double* partials = (double*)((char*)d_ws + PART_OFF);
    float* dist_arr = nullptr;
    size_t need = (size_t)DIST_OFF + (size_t)B * sizeof(float);
    if (ws_size >= need) dist_arr = (float*)((char*)d_ws + DIST_OFF);

    long ngroups = (B + 3) >> 2;

    // pass1: 2 groups per thread -> half the blocks
    long nhalf = (ngroups + 1) >> 1;
    int nb1 = (int)((nhalf + THREADS - 1) / THREADS);
    if (nb1 > PART_CAP) nb1 = PART_CAP;
    if (nb1 < 1) nb1 = 1;

    // pass2: 1 group per thread (unchanged from R8)
    int nb2 = (int)((ngroups + THREADS - 1) / THREADS);
    if (nb2 > PART_CAP) nb2 = PART_CAP;
    if (nb2 < 1) nb2 = 1;

    k_pass1<<<nb1, THREADS, 0, stream>>>(inp, tgt, dist_arr, blockmax, B);
    k_pass2<<<nb2, THREADS, 0, stream>>>(dist_arr, inp, tgt, blockmax, nb1, partials, B);
    k_final<<<1, THREADS, 0, stream>>>(partials, nb2, out, B);
}

// Round 10
// 132.276 us; speedup vs baseline: 1.8203x; 1.0056x over previous
//
#include <hip/hip_runtime.h>
#include <math.h>

// ---------------------------------------------------------------------------
// FocalLoss: geodetic->ECEF->ENU error -> distance -> focal-weighted RMS.
// 3-kernel pipeline: pass1 (dist -> d_ws, per-block max) ->
// pass2 (fold blockmax inline + focal + per-block partial) -> final.
//
// R10 = R9 with pass1 launch_bounds (256,2) -> (256,3): 12 waves/CU AND
// 2 groups/thread with hoisted loads. Latency-hiding = TLP x MLP:
// R8 = 12x6, R9 = 8x12, R10 = 12x12. Single-variable change.
// ---------------------------------------------------------------------------

#define THREADS 256
#define PART_CAP 8192
#define BMAX_OFF 64
#define PART_OFF (64 + PART_CAP * 4)                 // doubles, 8-aligned
#define DIST_OFF (1 << 20)                           // 1 MB, 16B-aligned

// ---- 8-wide breadth-first double sincos, |x| <= ~3.15 (no Payne-Hanek) ----
// fdlibm minimax, one term trimmed: abs err ~7e-12 -> 4e-5 m at N=6.4e6.
__device__ __forceinline__ void sincos8(const double* __restrict__ x,
                                        double* __restrict__ s,
                                        double* __restrict__ c) {
    const double TWO_OVER_PI = 0.636619772367581343076;
    const double PIO2_HI = 1.57079632679489655800e+00;
    const double PIO2_LO = 6.12323399573676603587e-17;

    double kd[8], r[8], r2[8];
    int q[8];
#pragma unroll
    for (int j = 0; j < 8; ++j) {
        kd[j] = rint(x[j] * TWO_OVER_PI);
        q[j] = ((int)kd[j]) & 3;
    }
#pragma unroll
    for (int j = 0; j < 8; ++j) {
        double rr = fma(-kd[j], PIO2_HI, x[j]);
        r[j] = fma(-kd[j], PIO2_LO, rr);
        r2[j] = r[j] * r[j];
    }
    double ps[8], pc[8];
#pragma unroll
    for (int j = 0; j < 8; ++j) { ps[j] = -2.50507602534068634195e-08;
                                  pc[j] =  2.08757232129817482790e-09; }
#pragma unroll
    for (int j = 0; j < 8; ++j) { ps[j] = fma(ps[j], r2[j],  2.75573137070700676789e-06);
                                  pc[j] = fma(pc[j], r2[j], -2.75573143513906633035e-07); }
#pragma unroll
    for (int j = 0; j < 8; ++j) { ps[j] = fma(ps[j], r2[j], -1.98412698298579493134e-04);
                                  pc[j] = fma(pc[j], r2[j],  2.48015872894767294178e-05); }
#pragma unroll
    for (int j = 0; j < 8; ++j) { ps[j] = fma(ps[j], r2[j],  8.33333333332248946124e-03);
                                  pc[j] = fma(pc[j], r2[j], -1.38888888888741095749e-03); }
#pragma unroll
    for (int j = 0; j < 8; ++j) { ps[j] = fma(ps[j], r2[j], -1.66666666666666324348e-01);
                                  pc[j] = fma(pc[j], r2[j],  4.16666666666666019037e-02); }
#pragma unroll
    for (int j = 0; j < 8; ++j) {
        double sv = fma(r2[j] * r[j], ps[j], r[j]);
        double cv = fma(r2[j] * r2[j], pc[j], fma(-0.5, r2[j], 1.0));
        double sr = (q[j] & 1) ? cv : sv;
        double cr = (q[j] & 1) ? sv : cv;
        s[j] = (q[j] & 2) ? -sr : sr;
        c[j] = ((q[j] + 1) & 2) ? -cr : cr;
    }
}

// ---- 4 elements, breadth-first sincos, NO rotation (|R d| == |d|) ----
__device__ __forceinline__ void dist_group4(const float* __restrict__ lat,
                                            const float* __restrict__ lon,
                                            const float* __restrict__ hh,
                                            const float* __restrict__ px,
                                            const float* __restrict__ py,
                                            const float* __restrict__ pz,
                                            float* __restrict__ dout) {
    const float D2R = (float)0.017453292519943295;   // fp32 deg2rad, matches numpy
    double x[8], s8[8], c8[8];
#pragma unroll
    for (int j = 0; j < 4; ++j) x[j] = (double)(lat[j] * D2R);
#pragma unroll
    for (int j = 0; j < 4; ++j) x[4 + j] = (double)(lon[j] * D2R);
    sincos8(x, s8, c8);

    const double A = 6378137.0, E2 = 0.00669437999014;
#pragma unroll
    for (int j = 0; j < 4; ++j) {
        double sl = s8[j], cl = c8[j], so = s8[4 + j], co = c8[4 + j];
        double h = (double)hh[j];
        double w = fma(-E2 * sl, sl, 1.0);            // [0.9933, 1]
        double y = fma(-0.5, w, 1.5);                 // rsqrt seed
        y = y * fma(-0.5 * w, y * y, 1.5);            // 2 Newton -> ~1e-19
        y = y * fma(-0.5 * w, y * y, 1.5);
        double N = A * y, Nh = N + h;
        double X = Nh * cl * co;
        double Y = Nh * cl * so;
        double Z = fma(N, -E2, N + h) * sl;           // (N*(1-E2)+h)*sl
        double dx = (double)px[j] - X;
        double dy = (double)py[j] - Y;
        double dz = (double)pz[j] - Z;
        dout[j] = sqrtf((float)(dx * dx + dy * dy + dz * dz));
    }
}

// scalar path for the tail
__device__ __forceinline__ float dist_one(float latd, float lond, float hf,
                                          float pxx, float pyy, float pzz) {
    float lat[4] = {latd, latd, latd, latd}, lon[4] = {lond, lond, lond, lond};
    float hh[4] = {hf, hf, hf, hf};
    float px[4] = {pxx, pxx, pxx, pxx}, py[4] = {pyy, pyy, pyy, pyy}, pz[4] = {pzz, pzz, pzz, pzz};
    float d[4];
    dist_group4(lat, lon, hh, px, py, pz, d);
    return d[0];
}

#define UNPACK4(ta, tb, tc, lat, lon, hh)                         \
    float lat[4] = {ta.x, ta.w, tb.z, tc.y};                      \
    float lon[4] = {ta.y, tb.x, tb.w, tc.z};                      \
    float hh[4]  = {ta.z, tb.y, tc.x, tc.w};

__global__ __launch_bounds__(THREADS, 3)
void k_pass1(const float* __restrict__ inp, const float* __restrict__ tgt,
             float* __restrict__ dist_arr, float* __restrict__ blockmax, long B) {
    long ngroups = (B + 3) >> 2;
    long nthreads = (long)gridDim.x * blockDim.x;     // = half of ngroups (rounded up)
    long gstride = 2 * nthreads;
    float lmax = 0.0f;
    for (long g = (long)blockIdx.x * blockDim.x + threadIdx.x; g < ngroups; g += gstride) {
        long gA = g;
        long gB = g + nthreads;                       // stride-separated partner group
        long baseA = gA << 2;
        long baseB = gB << 2;
        bool fastA = (baseA + 3 < B);
        bool fastB = (gB < ngroups) && (baseB + 3 < B);

        if (fastA && fastB) {
            // hoist ALL 12 loads before any compute (2x outstanding loads)
            const float4* tA = (const float4*)(tgt + 3 * baseA);
            const float4* pA = (const float4*)(inp + 3 * baseA);
            const float4* tB = (const float4*)(tgt + 3 * baseB);
            const float4* pB = (const float4*)(inp + 3 * baseB);
            float4 ta0 = tA[0], ta1 = tA[1], ta2 = tA[2];
            float4 pa0 = pA[0], pa1 = pA[1], pa2 = pA[2];
            float4 tb0 = tB[0], tb1 = tB[1], tb2 = tB[2];
            float4 pb0 = pB[0], pb1 = pB[1], pb2 = pB[2];

            UNPACK4(ta0, ta1, ta2, latA, lonA, hhA);
            UNPACK4(pa0, pa1, pa2, pxA, pyA, pzA);
            float dA[4];
            dist_group4(latA, lonA, hhA, pxA, pyA, pzA, dA);

            UNPACK4(tb0, tb1, tb2, latB, lonB, hhB);
            UNPACK4(pb0, pb1, pb2, pxB, pyB, pzB);
            float dB[4];
            dist_group4(latB, lonB, hhB, pxB, pyB, pzB, dB);

            if (dist_arr) {
                *(float4*)(dist_arr + baseA) = make_float4(dA[0], dA[1], dA[2], dA[3]);
                *(float4*)(dist_arr + baseB) = make_float4(dB[0], dB[1], dB[2], dB[3]);
            }
            lmax = fmaxf(lmax, fmaxf(fmaxf(dA[0], dA[1]), fmaxf(dA[2], dA[3])));
            lmax = fmaxf(lmax, fmaxf(fmaxf(dB[0], dB[1]), fmaxf(dB[2], dB[3])));
        } else {
            // slow path: handle each group scalar-safe
            for (int pass = 0; pass < 2; ++pass) {
                long gg = pass ? gB : gA;
                if (gg >= ngroups) continue;
                long base = gg << 2;
                long end = base + 4 < B ? base + 4 : B;
                for (long i = base; i < end; ++i) {
                    float d = dist_one(tgt[3*i], tgt[3*i+1], tgt[3*i+2],
                                       inp[3*i], inp[3*i+1], inp[3*i+2]);
                    if (dist_arr) dist_arr[i] = d;
                    lmax = fmaxf(lmax, d);
                }
            }
        }
    }
    for (int off = 32; off > 0; off >>= 1)
        lmax = fmaxf(lmax, __shfl_down(lmax, off, 64));
    __shared__ float smax[THREADS / 64];
    if ((threadIdx.x & 63) == 0) smax[threadIdx.x >> 6] = lmax;
    __syncthreads();
    if (threadIdx.x == 0) {
        float m = smax[0];
        for (int w = 1; w < THREADS / 64; ++w) m = fmaxf(m, smax[w]);
        blockmax[blockIdx.x] = m;
    }
}

__device__ __forceinline__ double focal2(float d, float denom) {
    float g = 2.0f * __expf(-d);                  // dynamic gamma (SCALE=1, GAMMA=2)
    float b = 1.0f - sqrtf(d / denom);            // true div: max elem ratio <= 1
    b = fmaxf(b, 0.0f);
    float wgt = __builtin_amdgcn_exp2f(g * __log2f(b));  // b^g; log2(0)->-inf->0 ok
    float fl = wgt * d;                           // ALPHA = 1
    return (double)fl * (double)fl;
}

__global__ void k_pass2(const float* __restrict__ dist_arr,
                        const float* __restrict__ inp,
                        const float* __restrict__ tgt,
                        const float* __restrict__ blockmax, int nb1,
                        double* __restrict__ partials, long B) {
    __shared__ float smax[THREADS / 64];
    __shared__ double sacc[THREADS / 64];
    __shared__ float sb;
    int tid = threadIdx.x;

    // fold blockmax inline (nb1 floats, L2-hot)
    float m = 0.0f;
    for (int i = tid; i < nb1; i += THREADS) m = fmaxf(m, blockmax[i]);
    for (int off = 32; off > 0; off >>= 1)
        m = fmaxf(m, __shfl_down(m, off, 64));
    if ((tid & 63) == 0) smax[tid >> 6] = m;
    __syncthreads();
    if (tid == 0) {
        float mm = smax[0];
        for (int w = 1; w < THREADS / 64; ++w) mm = fmaxf(mm, smax[w]);
        sb = mm;
    }
    __syncthreads();
    float denom = sb + 1e-8f;

    long ngroups = (B + 3) >> 2;
    long gstride = (long)gridDim.x * blockDim.x;
    double acc = 0.0;
    for (long g = (long)blockIdx.x * blockDim.x + tid; g < ngroups; g += gstride) {
        long base = g << 2;
        if (base + 3 < B) {
            float d0, d1, d2, d3;
            if (dist_arr) {
                float4 d4 = *(const float4*)(dist_arr + base);
                d0 = d4.x; d1 = d4.y; d2 = d4.z; d3 = d4.w;
            } else {
                const float4* t4 = (const float4*)(tgt + 3 * base);
                float4 ta = t4[0], tb = t4[1], tc = t4[2];
                const float4* p4 = (const float4*)(inp + 3 * base);
                float4 pa = p4[0], pb = p4[1], pc = p4[2];
                UNPACK4(ta, tb, tc, lat, lon, hh);
                UNPACK4(pa, pb, pc, px, py, pz);
                float d[4];
                dist_group4(lat, lon, hh, px, py, pz, d);
                d0 = d[0]; d1 = d[1]; d2 = d[2]; d3 = d[3];
            }
            acc += focal2(d0, denom) + focal2(d1, denom)
                 + focal2(d2, denom) + focal2(d3, denom);
        } else {
            for (long i = base; i < B; ++i) {
                float d = dist_arr ? dist_arr[i]
                                   : dist_one(tgt[3*i], tgt[3*i+1], tgt[3*i+2],
                                              inp[3*i], inp[3*i+1], inp[3*i+2]);
                acc += focal2(d, denom);
            }
        }
    }
    for (int off = 32; off > 0; off >>= 1)
        acc += __shfl_down(acc, off, 64);
    if ((tid & 63) == 0) sacc[tid >> 6] = acc;
    __syncthreads();
    if (tid == 0) {
        double s = sacc[0];
        for (int w = 1; w < THREADS / 64; ++w) s += sacc[w];
        partials[blockIdx.x] = s;
    }
}

__global__ void k_final(const double* __restrict__ partials, int nparts,
                        float* __restrict__ out, long B) {
    double acc = 0.0;
    for (int i = threadIdx.x; i < nparts; i += blockDim.x) acc += partials[i];
    for (int off = 32; off > 0; off >>= 1)
        acc += __shfl_down(acc, off, 64);
    __shared__ double lds[THREADS / 64];
    if ((threadIdx.x & 63) == 0) lds[threadIdx.x >> 6] = acc;
    __syncthreads();
    if (threadIdx.x == 0) {
        double s = lds[0];
        for (int w = 1; w < THREADS / 64; ++w) s += lds[w];
        out[0] = (float)sqrt(s / (double)B);
    }
}

extern "C" void kernel_launch(void* const* d_in, const int* in_sizes, int n_in,
                              void* d_out, int out_size, void* d_ws, size_t ws_size,
                              hipStream_t stream) {
    const float* inp = (const float*)d_in[0];   // (B,3) predicted ECEF
    const float* tgt = (const float*)d_in[1];   // (B,3) geodetic lat/lon/h
    float* out = (float*)d_out;
    long B = (long)in_sizes[0] / 3;

    float* blockmax = (float*)((char*)d_ws + BMAX_OFF);
    double* partials = (double*)((char*)d_ws + PART_OFF);
    float* dist_arr = nullptr;
    size_t need = (size_t)DIST_OFF + (size_t)B * sizeof(float);
    if (ws_size >= need) dist_arr = (float*)((char*)d_ws + DIST_OFF);

    long ngroups = (B + 3) >> 2;

    // pass1: 2 groups per thread -> half the blocks
    long nhalf = (ngroups + 1) >> 1;
    int nb1 = (int)((nhalf + THREADS - 1) / THREADS);
    if (nb1 > PART_CAP) nb1 = PART_CAP;
    if (nb1 < 1) nb1 = 1;

    // pass2: 1 group per thread
    int nb2 = (int)((ngroups + THREADS - 1) / THREADS);
    if (nb2 > PART_CAP) nb2 = PART_CAP;
    if (nb2 < 1) nb2 = 1;

    k_pass1<<<nb1, THREADS, 0, stream>>>(inp, tgt, dist_arr, blockmax, B);
    k_pass2<<<nb2, THREADS, 0, stream>>>(dist_arr, inp, tgt, blockmax, nb1, partials, B);
    k_final<<<1, THREADS, 0, stream>>>(partials, nb2, out, B);
}